// Round 1
// baseline (617.565 us; speedup 1.0000x reference)
//
#include <hip/hip_runtime.h>
#include <float.h>
#include <limits.h>
#include <math.h>

// ClusterLayer: B=131072 rows, K=1024 clusters, D=128.
// out (float32): [0] inertia/B, [1] xe/K, [2..2+B) cl as float.
//
// ws layout (bytes):
//   0    : double inertia_acc
//   8    : int    flag_cnt
//   16   : float  w2[1024]
//   4608 : int    flag_rows[...]   (near-tie rows needing f64 refinement)

#define BM 64
#define KT 64
#define XS 68              // padded LDS stride in floats (68*4=272 bytes, 16B aligned)
#define TAU 1e-3f          // near-tie gap threshold (f32 error ~2e-5 -> 40x margin)

__device__ __forceinline__ bool lexlt(float v1, int i1, float v2, int i2) {
    return v1 < v2 || (v1 == v2 && i1 < i2);
}

__global__ __launch_bounds__(256, 2)
void dist_argmin_kernel(const float* __restrict__ X, const float* __restrict__ W,
                        const float* __restrict__ w2, float* __restrict__ cl_out,
                        double* __restrict__ inertia_acc,
                        int* __restrict__ flag_cnt, int* __restrict__ flag_rows,
                        int flag_cap)
{
    // 70016 bytes static LDS (gfx950 allows up to 160KB/WG) -> 2 blocks/CU
    __shared__ float lx[128 * XS];          // transposed X tile: lx[d*XS + r]
    __shared__ float lw[128 * XS];          // transposed W tile: lw[d*XS + c]
    __shared__ float lx2[64];
    __shared__ double lred[16];

    const int tid = threadIdx.x;
    const int tr = tid >> 4;                // 0..15 -> rows 4*tr..4*tr+3
    const int tc = tid & 15;                // 0..15 -> clusters 4*tc..4*tc+3 (within tile)
    const int rowbase = blockIdx.x * BM;

    // ---- stage X tile (transposed), coalesced global reads ----
    for (int i = 0; i < 32; ++i) {
        int idx = i * 256 + tid;
        int r = idx >> 7;
        int d = idx & 127;
        lx[d * XS + r] = X[(size_t)(rowbase + r) * 128 + d];
    }
    __syncthreads();
    // per-row ||x||^2 (cancels in argmin; used for distance values / inertia)
    if (tid < 64) {
        float s = 0.f;
        for (int d = 0; d < 128; ++d) { float v = lx[d * XS + tid]; s = fmaf(v, v, s); }
        lx2[tid] = s;
    }
    __syncthreads();
    float rx2[4];
    #pragma unroll
    for (int j = 0; j < 4; ++j) rx2[j] = lx2[4 * tr + j];

    float m1v[4], m2v[4];
    int   m1i[4], m2i[4];
    #pragma unroll
    for (int j = 0; j < 4; ++j) { m1v[j] = FLT_MAX; m2v[j] = FLT_MAX; m1i[j] = INT_MAX; m2i[j] = INT_MAX; }

    const float* px = lx + 4 * tr;
    const float* pw = lw + 4 * tc;

    for (int ct = 0; ct < 1024; ct += KT) {
        __syncthreads();                    // previous tile's readers done
        for (int i = 0; i < 32; ++i) {
            int idx = i * 256 + tid;
            int c = idx >> 7;
            int d = idx & 127;
            lw[d * XS + c] = W[(size_t)(ct + c) * 128 + d];
        }
        __syncthreads();

        float acc[4][4];
        #pragma unroll
        for (int j = 0; j < 4; ++j)
            #pragma unroll
            for (int k = 0; k < 4; ++k) acc[j][k] = 0.f;

        #pragma unroll 8
        for (int d = 0; d < 128; ++d) {
            float4 xv = *reinterpret_cast<const float4*>(px + d * XS);
            float4 wv = *reinterpret_cast<const float4*>(pw + d * XS);
            float xa[4] = {xv.x, xv.y, xv.z, xv.w};
            float wa[4] = {wv.x, wv.y, wv.z, wv.w};
            #pragma unroll
            for (int j = 0; j < 4; ++j)
                #pragma unroll
                for (int k = 0; k < 4; ++k)
                    acc[j][k] = fmaf(xa[j], wa[k], acc[j][k]);
        }

        #pragma unroll
        for (int k = 0; k < 4; ++k) {
            int c = ct + 4 * tc + k;
            float w2c = w2[c];
            #pragma unroll
            for (int j = 0; j < 4; ++j) {
                float dist = fmaf(-2.f, acc[j][k], rx2[j] + w2c);
                if (lexlt(dist, c, m1v[j], m1i[j])) {
                    m2v[j] = m1v[j]; m2i[j] = m1i[j];
                    m1v[j] = dist;   m1i[j] = c;
                } else if (lexlt(dist, c, m2v[j], m2i[j])) {
                    m2v[j] = dist; m2i[j] = c;
                }
            }
        }
    }

    // ---- reduce top-2 across the 16 lanes (tc) sharing each row ----
    for (int off = 1; off < 16; off <<= 1) {
        #pragma unroll
        for (int j = 0; j < 4; ++j) {
            float ov1 = __shfl_xor(m1v[j], off, 64);
            int   oi1 = __shfl_xor(m1i[j], off, 64);
            float ov2 = __shfl_xor(m2v[j], off, 64);
            int   oi2 = __shfl_xor(m2i[j], off, 64);
            if (lexlt(ov1, oi1, m1v[j], m1i[j])) {
                float nv2; int ni2;
                if (lexlt(m1v[j], m1i[j], ov2, oi2)) { nv2 = m1v[j]; ni2 = m1i[j]; }
                else                                 { nv2 = ov2;    ni2 = oi2; }
                m1v[j] = ov1; m1i[j] = oi1;
                m2v[j] = nv2; m2i[j] = ni2;
            } else if (lexlt(ov1, oi1, m2v[j], m2i[j])) {
                m2v[j] = ov1; m2i[j] = oi1;
            }
        }
    }

    double local = 0.0;
    if (tc == 0) {
        for (int j = 0; j < 4; ++j) {
            int row = rowbase + 4 * tr + j;
            float gap = m2v[j] - m1v[j];
            if (gap >= TAU) {
                cl_out[row] = (float)m1i[j];
                local += (double)m1v[j];
            } else {
                int slot = atomicAdd(flag_cnt, 1);
                if (slot < flag_cap) {
                    flag_rows[slot] = row;       // resolved by refine_kernel
                } else {
                    cl_out[row] = (float)m1i[j]; // ws too small: accept f32 answer
                    local += (double)m1v[j];
                }
            }
        }
    }
    __syncthreads();
    if (tc == 0) lred[tr] = local;
    __syncthreads();
    if (tid == 0) {
        double t = 0.0;
        for (int i = 0; i < 16; ++i) t += lred[i];
        atomicAdd(inertia_acc, t);
    }
}

// exact f64 argmin over all 1024 clusters for flagged (near-tie) rows
__global__ void refine_kernel(const float* __restrict__ X, const float* __restrict__ W,
                              const int* __restrict__ flag_cnt, const int* __restrict__ flag_rows,
                              int flag_cap, float* __restrict__ cl_out,
                              double* __restrict__ inertia_acc)
{
    __shared__ double sv[4];
    __shared__ int    si[4];
    __shared__ float  xrow[128];
    int n = *flag_cnt;
    if (n > flag_cap) n = flag_cap;
    const int tid = threadIdx.x;

    for (int f = blockIdx.x; f < n; f += gridDim.x) {
        int row = flag_rows[f];
        if (tid < 128) xrow[tid] = X[(size_t)row * 128 + tid];
        __syncthreads();

        double best = DBL_MAX; int bi = INT_MAX;
        for (int cc = 0; cc < 4; ++cc) {
            int c = tid + 256 * cc;
            double dot = 0.0, wsq = 0.0;
            for (int d = 0; d < 128; ++d) {
                double wv = (double)W[(size_t)c * 128 + d];
                dot = fma((double)xrow[d], wv, dot);
                wsq = fma(wv, wv, wsq);
            }
            double dist = wsq - 2.0 * dot;   // x^2 omitted (constant per row)
            if (dist < best || (dist == best && c < bi)) { best = dist; bi = c; }
        }
        for (int off = 1; off < 64; off <<= 1) {
            double ov = __shfl_xor(best, off, 64);
            int    oi = __shfl_xor(bi, off, 64);
            if (ov < best || (ov == best && oi < bi)) { best = ov; bi = oi; }
        }
        if ((tid & 63) == 0) { sv[tid >> 6] = best; si[tid >> 6] = bi; }
        __syncthreads();
        if (tid == 0) {
            for (int wv = 1; wv < 4; ++wv)
                if (sv[wv] < best || (sv[wv] == best && si[wv] < bi)) { best = sv[wv]; bi = si[wv]; }
            double x2 = 0.0;
            for (int d = 0; d < 128; ++d) { double xv = (double)xrow[d]; x2 = fma(xv, xv, x2); }
            cl_out[row] = (float)bi;
            atomicAdd(inertia_acc, x2 + best);
        }
        __syncthreads();
    }
}

__global__ void w2_kernel(const float* __restrict__ W, float* __restrict__ w2)
{
    int k = blockIdx.x;
    int d = threadIdx.x;                       // 128 threads
    float v = W[(size_t)k * 128 + d];
    float sq = v * v;
    for (int off = 1; off < 64; off <<= 1) sq += __shfl_xor(sq, off, 64);
    __shared__ float p[2];
    if ((d & 63) == 0) p[d >> 6] = sq;
    __syncthreads();
    if (d == 0) w2[k] = p[0] + p[1];
}

__global__ void finalize_kernel(const float* __restrict__ W, const float* __restrict__ w2,
                                const double* __restrict__ inertia, float* __restrict__ out)
{
    __shared__ float sh1[128], sh2[128];
    int d = threadIdx.x;                       // 128 threads
    float s = 0.f;
    for (int k = 0; k < 1024; ++k) s += W[(size_t)k * 128 + d];
    float t = 0.f;
    for (int j = 0; j < 8; ++j) t += w2[d + 128 * j];
    sh1[d] = s * s;
    sh2[d] = t;
    __syncthreads();
    for (int off = 64; off > 0; off >>= 1) {
        if (d < off) { sh1[d] += sh1[d + off]; sh2[d] += sh2[d + off]; }
        __syncthreads();
    }
    if (d == 0) {
        float xe = 2.f * sh2[0] - sh1[0];      // 2*trace(G) - sum(G) = 2*Σ||w||² - ||Σw||²
        out[1] = xe / 1024.f;
        out[0] = (float)(*inertia / 131072.0);
    }
}

extern "C" void kernel_launch(void* const* d_in, const int* in_sizes, int n_in,
                              void* d_out, int out_size, void* d_ws, size_t ws_size,
                              hipStream_t stream)
{
    const float* X = (const float*)d_in[0];          // [131072,128] f32
    const float* W = (const float*)d_in[1];          // [1024,128]   f32
    float* out = (float*)d_out;                       // [131074]     f32
    char* ws = (char*)d_ws;

    double* inertia   = (double*)ws;
    int*    flag_cnt  = (int*)(ws + 8);
    float*  w2        = (float*)(ws + 16);
    int*    flag_rows = (int*)(ws + 4608);

    long cap_l = ((long)ws_size - 4608) / 4;
    int flag_cap = cap_l < 0 ? 0 : (cap_l > 131072 ? 131072 : (int)cap_l);

    hipMemsetAsync(ws, 0, 16, stream);               // inertia + flag_cnt

    w2_kernel<<<1024, 128, 0, stream>>>(W, w2);
    dist_argmin_kernel<<<2048, 256, 0, stream>>>(X, W, w2, out + 2, inertia,
                                                 flag_cnt, flag_rows, flag_cap);
    refine_kernel<<<1024, 256, 0, stream>>>(X, W, flag_cnt, flag_rows, flag_cap,
                                            out + 2, inertia);
    finalize_kernel<<<1, 128, 0, stream>>>(W, w2, inertia, out);
}

// Round 2
// 226.170 us; speedup vs baseline: 2.7305x; 2.7305x over previous
//
#include <hip/hip_runtime.h>
#include <float.h>
#include <limits.h>
#include <math.h>

// ClusterLayer: B=131072 rows, K=1024 clusters, D=128.
// out (float32): [0] inertia/B, [1] xe/K, [2..2+B) cl as float.
//
// R2: bf16 hi/lo split MFMA distance kernel (3-pass "3xTF32-style").
// dist = ||w||^2 - 2 x.w  (||x||^2 constant per row, added only for inertia).
// Top-2 tracking + f64 refine of near-ties (gap < TAU) keeps argmin exact.
//
// ws layout (bytes):
//   0    : double inertia_acc
//   8    : int    flag_cnt
//   16   : float  w2[1024]
//   8192 : int    flag_rows[...]

#define TAU 1e-3f

using bf16x8 = __attribute__((ext_vector_type(8))) short;
using f32x4  = __attribute__((ext_vector_type(4))) float;
using s16x4  = __attribute__((ext_vector_type(4))) short;

__device__ __forceinline__ short f2bf_trunc(float f) {
    return (short)(__float_as_uint(f) >> 16);
}
__device__ __forceinline__ float bf2f(short h) {
    return __uint_as_float(((unsigned int)(unsigned short)h) << 16);
}
__device__ __forceinline__ bool lexlt(float v1, int i1, float v2, int i2) {
    return v1 < v2 || (v1 == v2 && i1 < i2);
}

// LDS map (bytes):
//   A region:    0      + dt*32768 + (kb*128 + row)*16 + (d&7)*2      [dt in {h,l}]
//   B region:    65536  + dt*32768 + ((ntg*4 + k0b)*64 + lane)*16 + j*2
//   merge scr:   131072 .. +2048   (128 rows x 4 ints)
//   lx2:         133120 .. +512    (128 floats)
//   dred:        133632 .. +128    (16 doubles)
__global__ __launch_bounds__(512, 1)
void dist_argmin_kernel(const float* __restrict__ X, const float* __restrict__ W,
                        const float* __restrict__ w2g, float* __restrict__ cl_out,
                        double* __restrict__ inertia_acc,
                        int* __restrict__ flag_cnt, int* __restrict__ flag_rows,
                        int flag_cap)
{
    __shared__ __align__(16) char smem[133760];
    short*  Areg = (short*)smem;
    short*  Breg = (short*)(smem + 65536);
    int*    mscr = (int*)(smem + 131072);
    float*  lx2  = (float*)(smem + 131072 + 2048);
    double* dred = (double*)(smem + 131072 + 2048 + 512);

    const int tid    = threadIdx.x;
    const int lane   = tid & 63;
    const int laneLo = lane & 15;
    const int laneHi = lane >> 4;
    const int wid    = tid >> 6;
    const int rowg   = wid >> 1;      // 0..3 : rows rowg*32 .. +31
    const int colg   = wid & 1;       // 0..1 : cols colg*64 .. +63 (within 128-tile)
    const int rowbase = blockIdx.x * 128;

    // ---- stage A (X tile) with bf16 split, fragment-ordered layout + x2 ----
    {
        const int r = tid >> 2, q = tid & 3;
        float s = 0.f;
        #pragma unroll
        for (int j = 0; j < 8; ++j) {
            const int d0 = q * 4 + j * 16;
            float4 v = *reinterpret_cast<const float4*>(X + (size_t)(rowbase + r) * 128 + d0);
            float fv[4] = {v.x, v.y, v.z, v.w};
            s16x4 hv, lv;
            #pragma unroll
            for (int u = 0; u < 4; ++u) {
                s = fmaf(fv[u], fv[u], s);
                short h = f2bf_trunc(fv[u]);
                short l = f2bf_trunc(fv[u] - bf2f(h));
                hv[u] = h; lv[u] = l;
            }
            const int kb = d0 >> 3, off = d0 & 7;
            short* pa = Areg + (kb * 128 + r) * 8 + off;
            *reinterpret_cast<s16x4*>(pa)         = hv;
            *reinterpret_cast<s16x4*>(pa + 16384) = lv;   // +32768 bytes
        }
        s += __shfl_xor(s, 1, 64);
        s += __shfl_xor(s, 2, 64);
        if (q == 0) lx2[r] = s;
    }

    float t1v[2][4], t2v[2][4];
    int   t1i[2][4], t2i[2][4];
    #pragma unroll
    for (int m = 0; m < 2; ++m)
        #pragma unroll
        for (int r = 0; r < 4; ++r) {
            t1v[m][r] = FLT_MAX; t2v[m][r] = FLT_MAX;
            t1i[m][r] = INT_MAX; t2i[m][r] = INT_MAX;
        }

    const char* pAbase = smem + laneHi * 2048 + (rowg * 32 + laneLo) * 16;
    const char* pBbase = smem + 65536 + colg * 16384 + lane * 16;

    for (int iter = 0; iter < 8; ++iter) {
        __syncthreads();                 // prev tile's LDS readers done
        // ---- stage B (W tile, 128 clusters) with bf16 split ----
        {
            const int c = tid >> 2, q = tid & 3;
            const int nt = c >> 4, c15 = c & 15;
            #pragma unroll
            for (int j = 0; j < 8; ++j) {
                const int d0 = q * 4 + j * 16;
                float4 v = *reinterpret_cast<const float4*>(W + (size_t)(iter * 128 + c) * 128 + d0);
                float fv[4] = {v.x, v.y, v.z, v.w};
                s16x4 hv, lv;
                #pragma unroll
                for (int u = 0; u < 4; ++u) {
                    short h = f2bf_trunc(fv[u]);
                    short l = f2bf_trunc(fv[u] - bf2f(h));
                    hv[u] = h; lv[u] = l;
                }
                const int k0b = d0 >> 5, sub = (d0 >> 3) & 3, jj = d0 & 7;
                short* pb = Breg + ((nt * 4 + k0b) * 64 + sub * 16 + c15) * 8 + jj;
                *reinterpret_cast<s16x4*>(pb)         = hv;
                *reinterpret_cast<s16x4*>(pb + 16384) = lv;
            }
        }
        // w2 prefetch (L2-resident)
        float w2v[4];
        #pragma unroll
        for (int nt = 0; nt < 4; ++nt)
            w2v[nt] = w2g[iter * 128 + colg * 64 + nt * 16 + laneLo];
        __syncthreads();                 // B tile ready

        f32x4 acc[2][4];
        #pragma unroll
        for (int m = 0; m < 2; ++m)
            #pragma unroll
            for (int nt = 0; nt < 4; ++nt)
                acc[m][nt] = (f32x4){0.f, 0.f, 0.f, 0.f};

        #pragma unroll
        for (int k0b = 0; k0b < 4; ++k0b) {
            bf16x8 ah[2], al[2];
            #pragma unroll
            for (int m = 0; m < 2; ++m) {
                ah[m] = *reinterpret_cast<const bf16x8*>(pAbase + k0b * 8192 + m * 256);
                al[m] = *reinterpret_cast<const bf16x8*>(pAbase + 32768 + k0b * 8192 + m * 256);
            }
            #pragma unroll
            for (int nt = 0; nt < 4; ++nt) {
                bf16x8 bh = *reinterpret_cast<const bf16x8*>(pBbase + nt * 4096 + k0b * 1024);
                bf16x8 bl = *reinterpret_cast<const bf16x8*>(pBbase + 32768 + nt * 4096 + k0b * 1024);
                #pragma unroll
                for (int m = 0; m < 2; ++m) {
                    acc[m][nt] = __builtin_amdgcn_mfma_f32_16x16x32_bf16(ah[m], bh, acc[m][nt], 0, 0, 0);
                    acc[m][nt] = __builtin_amdgcn_mfma_f32_16x16x32_bf16(ah[m], bl, acc[m][nt], 0, 0, 0);
                    acc[m][nt] = __builtin_amdgcn_mfma_f32_16x16x32_bf16(al[m], bh, acc[m][nt], 0, 0, 0);
                }
            }
        }

        // ---- epilogue: dist = w2 - 2*dot, top-2 update (cols ascending -> strict <) ----
        #pragma unroll
        for (int nt = 0; nt < 4; ++nt) {
            const int col = iter * 128 + colg * 64 + nt * 16 + laneLo;
            #pragma unroll
            for (int m = 0; m < 2; ++m)
                #pragma unroll
                for (int r = 0; r < 4; ++r) {
                    float dv = fmaf(-2.f, acc[m][nt][r], w2v[nt]);
                    if (dv < t1v[m][r]) {
                        t2v[m][r] = t1v[m][r]; t2i[m][r] = t1i[m][r];
                        t1v[m][r] = dv;        t1i[m][r] = col;
                    } else if (dv < t2v[m][r]) {
                        t2v[m][r] = dv; t2i[m][r] = col;
                    }
                }
        }
    }

    // ---- reduce top-2 across the 16 col-lanes of each row ----
    #pragma unroll
    for (int off = 1; off < 16; off <<= 1) {
        #pragma unroll
        for (int m = 0; m < 2; ++m)
            #pragma unroll
            for (int r = 0; r < 4; ++r) {
                float ov1 = __shfl_xor(t1v[m][r], off, 64);
                int   oi1 = __shfl_xor(t1i[m][r], off, 64);
                float ov2 = __shfl_xor(t2v[m][r], off, 64);
                int   oi2 = __shfl_xor(t2i[m][r], off, 64);
                if (lexlt(ov1, oi1, t1v[m][r], t1i[m][r])) {
                    float nv2; int ni2;
                    if (lexlt(t1v[m][r], t1i[m][r], ov2, oi2)) { nv2 = t1v[m][r]; ni2 = t1i[m][r]; }
                    else                                       { nv2 = ov2;       ni2 = oi2; }
                    t1v[m][r] = ov1; t1i[m][r] = oi1;
                    t2v[m][r] = nv2; t2i[m][r] = ni2;
                } else if (lexlt(ov1, oi1, t2v[m][r], t2i[m][r])) {
                    t2v[m][r] = ov1; t2i[m][r] = oi1;
                }
            }
    }

    // ---- merge the two col-halves (colg 1 -> LDS -> colg 0) ----
    __syncthreads();
    if (colg == 1 && laneLo == 0) {
        #pragma unroll
        for (int m = 0; m < 2; ++m)
            #pragma unroll
            for (int r = 0; r < 4; ++r) {
                const int row = rowg * 32 + m * 16 + laneHi * 4 + r;
                mscr[row * 4 + 0] = __float_as_int(t1v[m][r]);
                mscr[row * 4 + 1] = t1i[m][r];
                mscr[row * 4 + 2] = __float_as_int(t2v[m][r]);
                mscr[row * 4 + 3] = t2i[m][r];
            }
    }
    __syncthreads();
    double local = 0.0;
    if (colg == 0 && laneLo == 0) {
        #pragma unroll
        for (int m = 0; m < 2; ++m)
            #pragma unroll
            for (int r = 0; r < 4; ++r) {
                const int row = rowg * 32 + m * 16 + laneHi * 4 + r;
                float ov1 = __int_as_float(mscr[row * 4 + 0]);
                int   oi1 = mscr[row * 4 + 1];
                float ov2 = __int_as_float(mscr[row * 4 + 2]);
                int   oi2 = mscr[row * 4 + 3];
                float b1v = t1v[m][r], b2v = t2v[m][r];
                int   b1i = t1i[m][r], b2i = t2i[m][r];
                if (lexlt(ov1, oi1, b1v, b1i)) {
                    if (lexlt(b1v, b1i, ov2, oi2)) { b2v = b1v; b2i = b1i; }
                    else                           { b2v = ov2; b2i = oi2; }
                    b1v = ov1; b1i = oi1;
                } else if (lexlt(ov1, oi1, b2v, b2i)) {
                    b2v = ov1; b2i = oi1;
                }
                const int grow = rowbase + row;
                const float gap = b2v - b1v;
                if (gap >= TAU) {
                    cl_out[grow] = (float)b1i;
                    local += (double)(b1v + lx2[row]);
                } else {
                    int slot = atomicAdd(flag_cnt, 1);
                    if (slot < flag_cap) {
                        flag_rows[slot] = grow;       // resolved exactly by refine_kernel
                    } else {
                        cl_out[grow] = (float)b1i;    // ws too small: accept approx
                        local += (double)(b1v + lx2[row]);
                    }
                }
            }
        dred[rowg * 4 + laneHi] = local;
    }
    __syncthreads();
    if (tid == 0) {
        double t = 0.0;
        for (int i = 0; i < 16; ++i) t += dred[i];
        atomicAdd(inertia_acc, t);
    }
}

// exact f64 argmin over all 1024 clusters for flagged (near-tie) rows
__global__ void refine_kernel(const float* __restrict__ X, const float* __restrict__ W,
                              const int* __restrict__ flag_cnt, const int* __restrict__ flag_rows,
                              int flag_cap, float* __restrict__ cl_out,
                              double* __restrict__ inertia_acc)
{
    __shared__ double sv[4];
    __shared__ int    si[4];
    __shared__ float  xrow[128];
    int n = *flag_cnt;
    if (n > flag_cap) n = flag_cap;
    const int tid = threadIdx.x;

    for (int f = blockIdx.x; f < n; f += gridDim.x) {
        int row = flag_rows[f];
        if (tid < 128) xrow[tid] = X[(size_t)row * 128 + tid];
        __syncthreads();

        double best = DBL_MAX; int bi = INT_MAX;
        for (int cc = 0; cc < 4; ++cc) {
            int c = tid + 256 * cc;
            double dot = 0.0, wsq = 0.0;
            for (int d = 0; d < 128; ++d) {
                double wv = (double)W[(size_t)c * 128 + d];
                dot = fma((double)xrow[d], wv, dot);
                wsq = fma(wv, wv, wsq);
            }
            double dist = wsq - 2.0 * dot;   // x^2 omitted (constant per row)
            if (dist < best || (dist == best && c < bi)) { best = dist; bi = c; }
        }
        for (int off = 1; off < 64; off <<= 1) {
            double ov = __shfl_xor(best, off, 64);
            int    oi = __shfl_xor(bi, off, 64);
            if (ov < best || (ov == best && oi < bi)) { best = ov; bi = oi; }
        }
        if ((tid & 63) == 0) { sv[tid >> 6] = best; si[tid >> 6] = bi; }
        __syncthreads();
        if (tid == 0) {
            for (int wv = 1; wv < 4; ++wv)
                if (sv[wv] < best || (sv[wv] == best && si[wv] < bi)) { best = sv[wv]; bi = si[wv]; }
            double x2 = 0.0;
            for (int d = 0; d < 128; ++d) { double xv = (double)xrow[d]; x2 = fma(xv, xv, x2); }
            cl_out[row] = (float)bi;
            atomicAdd(inertia_acc, x2 + best);
        }
        __syncthreads();
    }
}

__global__ void w2_kernel(const float* __restrict__ W, float* __restrict__ w2)
{
    int k = blockIdx.x;
    int d = threadIdx.x;                       // 128 threads
    float v = W[(size_t)k * 128 + d];
    float sq = v * v;
    for (int off = 1; off < 64; off <<= 1) sq += __shfl_xor(sq, off, 64);
    __shared__ float p[2];
    if ((d & 63) == 0) p[d >> 6] = sq;
    __syncthreads();
    if (d == 0) w2[k] = p[0] + p[1];
}

__global__ void finalize_kernel(const float* __restrict__ W, const float* __restrict__ w2,
                                const double* __restrict__ inertia, float* __restrict__ out)
{
    __shared__ float sh1[128], sh2[128];
    int d = threadIdx.x;                       // 128 threads
    float s = 0.f;
    for (int k = 0; k < 1024; ++k) s += W[(size_t)k * 128 + d];
    float t = 0.f;
    for (int j = 0; j < 8; ++j) t += w2[d + 128 * j];
    sh1[d] = s * s;
    sh2[d] = t;
    __syncthreads();
    for (int off = 64; off > 0; off >>= 1) {
        if (d < off) { sh1[d] += sh1[d + off]; sh2[d] += sh2[d + off]; }
        __syncthreads();
    }
    if (d == 0) {
        float xe = 2.f * sh2[0] - sh1[0];      // 2*trace(G) - sum(G) = 2*Σ||w||² - ||Σw||²
        out[1] = xe / 1024.f;
        out[0] = (float)(*inertia / 131072.0);
    }
}

extern "C" void kernel_launch(void* const* d_in, const int* in_sizes, int n_in,
                              void* d_out, int out_size, void* d_ws, size_t ws_size,
                              hipStream_t stream)
{
    const float* X = (const float*)d_in[0];          // [131072,128] f32
    const float* W = (const float*)d_in[1];          // [1024,128]   f32
    float* out = (float*)d_out;                       // [131074]     f32
    char* ws = (char*)d_ws;

    double* inertia   = (double*)ws;
    int*    flag_cnt  = (int*)(ws + 8);
    float*  w2        = (float*)(ws + 16);
    int*    flag_rows = (int*)(ws + 8192);

    long cap_l = ((long)ws_size - 8192) / 4;
    int flag_cap = cap_l < 0 ? 0 : (cap_l > 131072 ? 131072 : (int)cap_l);

    hipMemsetAsync(ws, 0, 16, stream);               // inertia + flag_cnt

    w2_kernel<<<1024, 128, 0, stream>>>(W, w2);
    dist_argmin_kernel<<<1024, 512, 0, stream>>>(X, W, w2, out + 2, inertia,
                                                 flag_cnt, flag_rows, flag_cap);
    refine_kernel<<<1024, 256, 0, stream>>>(X, W, flag_cnt, flag_rows, flag_cap,
                                            out + 2, inertia);
    finalize_kernel<<<1, 128, 0, stream>>>(W, w2, inertia, out);
}

// Round 3
// 202.292 us; speedup vs baseline: 3.0528x; 1.1180x over previous
//
#include <hip/hip_runtime.h>
#include <float.h>
#include <limits.h>
#include <math.h>

// ClusterLayer: B=131072 rows, K=1024 clusters, D=128.
// out (float32): [0] inertia/B, [1] xe/K, [2..2+B) cl as float.
//
// R3: bf16 hi/lo 3-pass MFMA + precomputed W-split in ws (B staged via
// global_load_lds into double-buffered LDS with counted vmcnt), A fragments
// in registers, branch-free top-2 epilogue. f64 refine of near-ties.
//
// ws layout (bytes):
//   0      : double inertia_acc
//   8      : int    flag_cnt
//   16     : float  w2[1024]
//   8192   : short  whl[tile 0..7][h/l fragment image]   (524288 B)
//   532480 : int    flag_rows[...]

#define TAU 1e-3f

using bf16x8 = __attribute__((ext_vector_type(8))) short;
using f32x4  = __attribute__((ext_vector_type(4))) float;
using s16x4  = __attribute__((ext_vector_type(4))) short;

static __device__ __forceinline__ short f2bf_trunc(float f) {
    return (short)(__float_as_uint(f) >> 16);
}
static __device__ __forceinline__ float bf2f(short h) {
    return __uint_as_float(((unsigned int)(unsigned short)h) << 16);
}
static __device__ __forceinline__ bool lexlt(float v1, int i1, float v2, int i2) {
    return v1 < v2 || (v1 == v2 && i1 < i2);
}
static __device__ __forceinline__ void gload_lds16(const void* g, void* l) {
    __builtin_amdgcn_global_load_lds(
        (const __attribute__((address_space(1))) unsigned int*)g,
        (__attribute__((address_space(3))) unsigned int*)l, 16, 0, 0);
}
#define FENCE() do { asm volatile("" ::: "memory"); __builtin_amdgcn_sched_barrier(0); } while (0)

// W prep: w2 per cluster + (optionally) bf16 hi/lo split written in the exact
// per-tile LDS fragment-image order consumed by dist_argmin_mfma.
__global__ void wprep_kernel(const float* __restrict__ W, float* __restrict__ w2,
                             short* __restrict__ whl, int write_whl)
{
    const int k = blockIdx.x;      // cluster
    const int d = threadIdx.x;     // 0..127 dim
    float v = W[(size_t)k * 128 + d];
    float sq = v * v;
    for (int off = 1; off < 64; off <<= 1) sq += __shfl_xor(sq, off, 64);
    __shared__ float p[2];
    if ((d & 63) == 0) p[d >> 6] = sq;
    __syncthreads();
    if (d == 0) w2[k] = p[0] + p[1];
    if (write_whl) {
        short h = f2bf_trunc(v);
        short l = f2bf_trunc(v - bf2f(h));
        const int tile = k >> 7, c = k & 127;
        // shorts: tile*32768 + (c>>4)*2048 + (d>>5)*512 + ((d>>3)&3)*128 + (c&15)*8 + (d&7)
        size_t base = (size_t)tile * 32768 + (size_t)(c >> 4) * 2048 + (size_t)(d >> 5) * 512
                    + (size_t)((d >> 3) & 3) * 128 + (size_t)(c & 15) * 8 + (size_t)(d & 7);
        whl[base]         = h;
        whl[base + 16384] = l;     // +32768 bytes: lo plane
    }
}

// LDS map (bytes):
//   lB0: 0..65536      B tile buf0 (h 32KB + l 32KB); also A image in prologue
//   lB1: 65536..131072 B tile buf1
//   lw2: 131072 (+4096)
//   lx2: 135168 (+512)
//   mscr:135680 (+2048)
//   dred:137728 (+128)
__global__ __launch_bounds__(512, 1)
void dist_argmin_mfma(const float* __restrict__ X, const short* __restrict__ whl,
                      const float* __restrict__ w2g, float* __restrict__ cl_out,
                      double* __restrict__ inertia_acc,
                      int* __restrict__ flag_cnt, int* __restrict__ flag_rows,
                      int flag_cap)
{
    __shared__ __align__(16) char smem[137856];
    char*   lB0  = smem;
    char*   lB1  = smem + 65536;
    float*  lw2  = (float*)(smem + 131072);
    float*  lx2  = (float*)(smem + 135168);
    int*    mscr = (int*)(smem + 135680);
    double* dred = (double*)(smem + 137728);

    const int tid    = threadIdx.x;
    const int lane   = tid & 63;
    const int laneLo = lane & 15;
    const int laneHi = lane >> 4;
    const int wid    = tid >> 6;
    const int rowg   = wid >> 1;
    const int colg   = wid & 1;
    const int rowbase = blockIdx.x * 128;

    // w2 -> LDS
    lw2[tid]       = w2g[tid];
    lw2[tid + 512] = w2g[tid + 512];

    // ---- A conversion into lB0 (fragment image) + per-row ||x||^2 ----
    {
        const int r = tid >> 2, q = tid & 3;
        float s = 0.f;
        short* Areg = (short*)lB0;
        #pragma unroll
        for (int j = 0; j < 8; ++j) {
            const int d0 = q * 4 + j * 16;
            float4 v = *reinterpret_cast<const float4*>(X + (size_t)(rowbase + r) * 128 + d0);
            float fv[4] = {v.x, v.y, v.z, v.w};
            s16x4 hv, lv;
            #pragma unroll
            for (int u = 0; u < 4; ++u) {
                s = fmaf(fv[u], fv[u], s);
                short h = f2bf_trunc(fv[u]);
                short l = f2bf_trunc(fv[u] - bf2f(h));
                hv[u] = h; lv[u] = l;
            }
            const int kb = d0 >> 3, off = d0 & 7;
            short* pa = Areg + ((size_t)kb * 128 + r) * 8 + off;
            *reinterpret_cast<s16x4*>(pa)         = hv;
            *reinterpret_cast<s16x4*>(pa + 16384) = lv;
        }
        s += __shfl_xor(s, 1, 64);
        s += __shfl_xor(s, 2, 64);
        if (q == 0) lx2[r] = s;
    }
    __syncthreads();

    // ---- A fragments to registers (held for the whole kernel) ----
    bf16x8 ah[2][4], al[2][4];
    {
        const char* pA = lB0 + laneHi * 2048 + (rowg * 32 + laneLo) * 16;
        #pragma unroll
        for (int k0b = 0; k0b < 4; ++k0b)
            #pragma unroll
            for (int m = 0; m < 2; ++m) {
                ah[m][k0b] = *reinterpret_cast<const bf16x8*>(pA + k0b * 8192 + m * 256);
                al[m][k0b] = *reinterpret_cast<const bf16x8*>(pA + 32768 + k0b * 8192 + m * 256);
            }
    }
    asm volatile("s_waitcnt lgkmcnt(0)" ::: "memory");
    __builtin_amdgcn_sched_barrier(0);
    __builtin_amdgcn_s_barrier();          // all waves done reading A image
    FENCE();

    // ---- issue B[0] -> lB0 ----
    #pragma unroll
    for (int q = 0; q < 8; ++q)
        gload_lds16((const char*)whl + (q * 8 + wid) * 1024 + lane * 16,
                    lB0 + (q * 8 + wid) * 1024);

    float t1v[2][4], t2v[2][4];
    int   t1i[2][4];
    #pragma unroll
    for (int m = 0; m < 2; ++m)
        #pragma unroll
        for (int r = 0; r < 4; ++r) {
            t1v[m][r] = FLT_MAX; t2v[m][r] = FLT_MAX; t1i[m][r] = INT_MAX;
        }
    int colv[4];
    #pragma unroll
    for (int nt = 0; nt < 4; ++nt) colv[nt] = colg * 64 + nt * 16 + laneLo;

    const char* pB0 = lB0 + colg * 16384 + lane * 16;
    const char* pB1 = lB1 + colg * 16384 + lane * 16;

    auto compute = [&](int t, const char* pB) {
        float w2v[4];
        #pragma unroll
        for (int nt = 0; nt < 4; ++nt)
            w2v[nt] = lw2[t * 128 + colg * 64 + nt * 16 + laneLo];

        f32x4 acc[2][4];
        #pragma unroll
        for (int m = 0; m < 2; ++m)
            #pragma unroll
            for (int nt = 0; nt < 4; ++nt)
                acc[m][nt] = (f32x4){0.f, 0.f, 0.f, 0.f};

        __builtin_amdgcn_s_setprio(1);
        #pragma unroll
        for (int k0b = 0; k0b < 4; ++k0b) {
            #pragma unroll
            for (int nt = 0; nt < 4; ++nt) {
                bf16x8 bh = *reinterpret_cast<const bf16x8*>(pB + nt * 4096 + k0b * 1024);
                bf16x8 bl = *reinterpret_cast<const bf16x8*>(pB + 32768 + nt * 4096 + k0b * 1024);
                #pragma unroll
                for (int m = 0; m < 2; ++m) {
                    acc[m][nt] = __builtin_amdgcn_mfma_f32_16x16x32_bf16(ah[m][k0b], bh, acc[m][nt], 0, 0, 0);
                    acc[m][nt] = __builtin_amdgcn_mfma_f32_16x16x32_bf16(ah[m][k0b], bl, acc[m][nt], 0, 0, 0);
                    acc[m][nt] = __builtin_amdgcn_mfma_f32_16x16x32_bf16(al[m][k0b], bh, acc[m][nt], 0, 0, 0);
                }
            }
        }
        __builtin_amdgcn_s_setprio(0);

        // dist = w2 - 2*dot; branch-free top-2 (value) + top-1 index.
        // strict < with ascending col order => first-occurrence argmin.
        #pragma unroll
        for (int nt = 0; nt < 4; ++nt)
            #pragma unroll
            for (int m = 0; m < 2; ++m)
                #pragma unroll
                for (int r = 0; r < 4; ++r) {
                    float dv = fmaf(-2.f, acc[m][nt][r], w2v[nt]);
                    float hi = fmaxf(t1v[m][r], dv);
                    t2v[m][r] = fminf(t2v[m][r], hi);
                    bool cnd = dv < t1v[m][r];
                    t1i[m][r] = cnd ? colv[nt] : t1i[m][r];
                    t1v[m][r] = fminf(t1v[m][r], dv);
                }
        #pragma unroll
        for (int nt = 0; nt < 4; ++nt) colv[nt] += 128;
    };

    #pragma unroll 2
    for (int t = 0; t < 7; ++t) {
        // issue B[t+1] into the other buffer (previous readers finished at the
        // end-of-iter barrier of t-1)
        char* dst = ((t + 1) & 1) ? lB1 : lB0;
        const char* src = (const char*)whl + (size_t)(t + 1) * 65536;
        #pragma unroll
        for (int q = 0; q < 8; ++q)
            gload_lds16(src + (q * 8 + wid) * 1024 + lane * 16,
                        dst + (q * 8 + wid) * 1024);
        asm volatile("s_waitcnt vmcnt(8)" ::: "memory");   // my B[t] landed; B[t+1] stays in flight
        __builtin_amdgcn_sched_barrier(0);
        __builtin_amdgcn_s_barrier();                      // everyone's B[t] landed
        FENCE();
        compute(t, (t & 1) ? pB1 : pB0);
        asm volatile("s_waitcnt lgkmcnt(0)" ::: "memory");
        __builtin_amdgcn_sched_barrier(0);
        __builtin_amdgcn_s_barrier();                      // all waves done reading buf[t&1]
        FENCE();
    }
    asm volatile("s_waitcnt vmcnt(0)" ::: "memory");
    __builtin_amdgcn_sched_barrier(0);
    __builtin_amdgcn_s_barrier();
    FENCE();
    compute(7, pB1);

    // ---- reduce top-2 across the 16 col-lanes of each row ----
    #pragma unroll
    for (int off = 1; off < 16; off <<= 1) {
        #pragma unroll
        for (int m = 0; m < 2; ++m)
            #pragma unroll
            for (int r = 0; r < 4; ++r) {
                float ov1 = __shfl_xor(t1v[m][r], off, 64);
                int   oi1 = __shfl_xor(t1i[m][r], off, 64);
                float ov2 = __shfl_xor(t2v[m][r], off, 64);
                float nt2 = fminf(fminf(t2v[m][r], ov2), fmaxf(t1v[m][r], ov1));
                if (lexlt(ov1, oi1, t1v[m][r], t1i[m][r])) { t1v[m][r] = ov1; t1i[m][r] = oi1; }
                t2v[m][r] = nt2;
            }
    }

    // ---- merge col-halves via LDS ----
    __syncthreads();
    if (colg == 1 && laneLo == 0) {
        #pragma unroll
        for (int m = 0; m < 2; ++m)
            #pragma unroll
            for (int r = 0; r < 4; ++r) {
                const int row = rowg * 32 + m * 16 + laneHi * 4 + r;
                mscr[row * 4 + 0] = __float_as_int(t1v[m][r]);
                mscr[row * 4 + 1] = t1i[m][r];
                mscr[row * 4 + 2] = __float_as_int(t2v[m][r]);
            }
    }
    __syncthreads();
    double local = 0.0;
    if (colg == 0 && laneLo == 0) {
        #pragma unroll
        for (int m = 0; m < 2; ++m)
            #pragma unroll
            for (int r = 0; r < 4; ++r) {
                const int row = rowg * 32 + m * 16 + laneHi * 4 + r;
                float ov1 = __int_as_float(mscr[row * 4 + 0]);
                int   oi1 = mscr[row * 4 + 1];
                float ov2 = __int_as_float(mscr[row * 4 + 2]);
                float b1v = t1v[m][r], b2v;
                int   b1i = t1i[m][r];
                b2v = fminf(fminf(t2v[m][r], ov2), fmaxf(b1v, ov1));
                if (lexlt(ov1, oi1, b1v, b1i)) { b1v = ov1; b1i = oi1; }
                const int grow = rowbase + row;
                const float gap = b2v - b1v;
                if (gap >= TAU) {
                    cl_out[grow] = (float)b1i;
                    local += (double)(b1v + lx2[row]);
                } else {
                    int slot = atomicAdd(flag_cnt, 1);
                    if (slot < flag_cap) {
                        flag_rows[slot] = grow;
                    } else {
                        cl_out[grow] = (float)b1i;
                        local += (double)(b1v + lx2[row]);
                    }
                }
            }
        dred[rowg * 4 + laneHi] = local;
    }
    __syncthreads();
    if (tid == 0) {
        double tt = 0.0;
        for (int i = 0; i < 16; ++i) tt += dred[i];
        atomicAdd(inertia_acc, tt);
    }
}

// ---------------- fallback (R2 kernel, used if ws too small) ----------------
__global__ __launch_bounds__(512, 1)
void dist_argmin_v2(const float* __restrict__ X, const float* __restrict__ W,
                    const float* __restrict__ w2g, float* __restrict__ cl_out,
                    double* __restrict__ inertia_acc,
                    int* __restrict__ flag_cnt, int* __restrict__ flag_rows,
                    int flag_cap)
{
    __shared__ __align__(16) char smem[133760];
    short*  Areg = (short*)smem;
    short*  Breg = (short*)(smem + 65536);
    int*    mscr = (int*)(smem + 131072);
    float*  lx2  = (float*)(smem + 131072 + 2048);
    double* dred = (double*)(smem + 131072 + 2048 + 512);

    const int tid    = threadIdx.x;
    const int lane   = tid & 63;
    const int laneLo = lane & 15;
    const int laneHi = lane >> 4;
    const int wid    = tid >> 6;
    const int rowg   = wid >> 1;
    const int colg   = wid & 1;
    const int rowbase = blockIdx.x * 128;

    {
        const int r = tid >> 2, q = tid & 3;
        float s = 0.f;
        #pragma unroll
        for (int j = 0; j < 8; ++j) {
            const int d0 = q * 4 + j * 16;
            float4 v = *reinterpret_cast<const float4*>(X + (size_t)(rowbase + r) * 128 + d0);
            float fv[4] = {v.x, v.y, v.z, v.w};
            s16x4 hv, lv;
            #pragma unroll
            for (int u = 0; u < 4; ++u) {
                s = fmaf(fv[u], fv[u], s);
                short h = f2bf_trunc(fv[u]);
                short l = f2bf_trunc(fv[u] - bf2f(h));
                hv[u] = h; lv[u] = l;
            }
            const int kb = d0 >> 3, off = d0 & 7;
            short* pa = Areg + (kb * 128 + r) * 8 + off;
            *reinterpret_cast<s16x4*>(pa)         = hv;
            *reinterpret_cast<s16x4*>(pa + 16384) = lv;
        }
        s += __shfl_xor(s, 1, 64);
        s += __shfl_xor(s, 2, 64);
        if (q == 0) lx2[r] = s;
    }

    float t1v[2][4], t2v[2][4];
    int   t1i[2][4];
    #pragma unroll
    for (int m = 0; m < 2; ++m)
        #pragma unroll
        for (int r = 0; r < 4; ++r) {
            t1v[m][r] = FLT_MAX; t2v[m][r] = FLT_MAX; t1i[m][r] = INT_MAX;
        }

    const char* pAbase = smem + laneHi * 2048 + (rowg * 32 + laneLo) * 16;
    const char* pBbase = smem + 65536 + colg * 16384 + lane * 16;

    for (int iter = 0; iter < 8; ++iter) {
        __syncthreads();
        {
            const int c = tid >> 2, q = tid & 3;
            const int nt = c >> 4, c15 = c & 15;
            #pragma unroll
            for (int j = 0; j < 8; ++j) {
                const int d0 = q * 4 + j * 16;
                float4 v = *reinterpret_cast<const float4*>(W + (size_t)(iter * 128 + c) * 128 + d0);
                float fv[4] = {v.x, v.y, v.z, v.w};
                s16x4 hv, lv;
                #pragma unroll
                for (int u = 0; u < 4; ++u) {
                    short h = f2bf_trunc(fv[u]);
                    short l = f2bf_trunc(fv[u] - bf2f(h));
                    hv[u] = h; lv[u] = l;
                }
                const int k0b = d0 >> 5, sub = (d0 >> 3) & 3, jj = d0 & 7;
                short* pb = Breg + ((nt * 4 + k0b) * 64 + sub * 16 + c15) * 8 + jj;
                *reinterpret_cast<s16x4*>(pb)         = hv;
                *reinterpret_cast<s16x4*>(pb + 16384) = lv;
            }
        }
        float w2v[4];
        #pragma unroll
        for (int nt = 0; nt < 4; ++nt)
            w2v[nt] = w2g[iter * 128 + colg * 64 + nt * 16 + laneLo];
        __syncthreads();

        f32x4 acc[2][4];
        #pragma unroll
        for (int m = 0; m < 2; ++m)
            #pragma unroll
            for (int nt = 0; nt < 4; ++nt)
                acc[m][nt] = (f32x4){0.f, 0.f, 0.f, 0.f};

        #pragma unroll
        for (int k0b = 0; k0b < 4; ++k0b) {
            bf16x8 ah[2], al[2];
            #pragma unroll
            for (int m = 0; m < 2; ++m) {
                ah[m] = *reinterpret_cast<const bf16x8*>(pAbase + k0b * 8192 + m * 256);
                al[m] = *reinterpret_cast<const bf16x8*>(pAbase + 32768 + k0b * 8192 + m * 256);
            }
            #pragma unroll
            for (int nt = 0; nt < 4; ++nt) {
                bf16x8 bh = *reinterpret_cast<const bf16x8*>(pBbase + nt * 4096 + k0b * 1024);
                bf16x8 bl = *reinterpret_cast<const bf16x8*>(pBbase + 32768 + nt * 4096 + k0b * 1024);
                #pragma unroll
                for (int m = 0; m < 2; ++m) {
                    acc[m][nt] = __builtin_amdgcn_mfma_f32_16x16x32_bf16(ah[m], bh, acc[m][nt], 0, 0, 0);
                    acc[m][nt] = __builtin_amdgcn_mfma_f32_16x16x32_bf16(ah[m], bl, acc[m][nt], 0, 0, 0);
                    acc[m][nt] = __builtin_amdgcn_mfma_f32_16x16x32_bf16(al[m], bh, acc[m][nt], 0, 0, 0);
                }
            }
        }

        #pragma unroll
        for (int nt = 0; nt < 4; ++nt) {
            const int col = iter * 128 + colg * 64 + nt * 16 + laneLo;
            #pragma unroll
            for (int m = 0; m < 2; ++m)
                #pragma unroll
                for (int r = 0; r < 4; ++r) {
                    float dv = fmaf(-2.f, acc[m][nt][r], w2v[nt]);
                    float hi = fmaxf(t1v[m][r], dv);
                    t2v[m][r] = fminf(t2v[m][r], hi);
                    bool cnd = dv < t1v[m][r];
                    t1i[m][r] = cnd ? col : t1i[m][r];
                    t1v[m][r] = fminf(t1v[m][r], dv);
                }
        }
    }

    #pragma unroll
    for (int off = 1; off < 16; off <<= 1) {
        #pragma unroll
        for (int m = 0; m < 2; ++m)
            #pragma unroll
            for (int r = 0; r < 4; ++r) {
                float ov1 = __shfl_xor(t1v[m][r], off, 64);
                int   oi1 = __shfl_xor(t1i[m][r], off, 64);
                float ov2 = __shfl_xor(t2v[m][r], off, 64);
                float nt2 = fminf(fminf(t2v[m][r], ov2), fmaxf(t1v[m][r], ov1));
                if (lexlt(ov1, oi1, t1v[m][r], t1i[m][r])) { t1v[m][r] = ov1; t1i[m][r] = oi1; }
                t2v[m][r] = nt2;
            }
    }

    __syncthreads();
    if (colg == 1 && laneLo == 0) {
        #pragma unroll
        for (int m = 0; m < 2; ++m)
            #pragma unroll
            for (int r = 0; r < 4; ++r) {
                const int row = rowg * 32 + m * 16 + laneHi * 4 + r;
                mscr[row * 4 + 0] = __float_as_int(t1v[m][r]);
                mscr[row * 4 + 1] = t1i[m][r];
                mscr[row * 4 + 2] = __float_as_int(t2v[m][r]);
            }
    }
    __syncthreads();
    double local = 0.0;
    if (colg == 0 && laneLo == 0) {
        #pragma unroll
        for (int m = 0; m < 2; ++m)
            #pragma unroll
            for (int r = 0; r < 4; ++r) {
                const int row = rowg * 32 + m * 16 + laneHi * 4 + r;
                float ov1 = __int_as_float(mscr[row * 4 + 0]);
                int   oi1 = mscr[row * 4 + 1];
                float ov2 = __int_as_float(mscr[row * 4 + 2]);
                float b1v = t1v[m][r], b2v;
                int   b1i = t1i[m][r];
                b2v = fminf(fminf(t2v[m][r], ov2), fmaxf(b1v, ov1));
                if (lexlt(ov1, oi1, b1v, b1i)) { b1v = ov1; b1i = oi1; }
                const int grow = rowbase + row;
                const float gap = b2v - b1v;
                if (gap >= TAU) {
                    cl_out[grow] = (float)b1i;
                    local += (double)(b1v + lx2[row]);
                } else {
                    int slot = atomicAdd(flag_cnt, 1);
                    if (slot < flag_cap) flag_rows[slot] = grow;
                    else { cl_out[grow] = (float)b1i; local += (double)(b1v + lx2[row]); }
                }
            }
        dred[rowg * 4 + laneHi] = local;
    }
    __syncthreads();
    if (tid == 0) {
        double t = 0.0;
        for (int i = 0; i < 16; ++i) t += dred[i];
        atomicAdd(inertia_acc, t);
    }
}

// exact f64 argmin over all 1024 clusters for flagged (near-tie) rows
__global__ void refine_kernel(const float* __restrict__ X, const float* __restrict__ W,
                              const int* __restrict__ flag_cnt, const int* __restrict__ flag_rows,
                              int flag_cap, float* __restrict__ cl_out,
                              double* __restrict__ inertia_acc)
{
    __shared__ double sv[4];
    __shared__ int    si[4];
    __shared__ float  xrow[128];
    int n = *flag_cnt;
    if (n > flag_cap) n = flag_cap;
    const int tid = threadIdx.x;

    for (int f = blockIdx.x; f < n; f += gridDim.x) {
        int row = flag_rows[f];
        if (tid < 128) xrow[tid] = X[(size_t)row * 128 + tid];
        __syncthreads();

        double best = DBL_MAX; int bi = INT_MAX;
        for (int cc = 0; cc < 4; ++cc) {
            int c = tid + 256 * cc;
            double dot = 0.0, wsq = 0.0;
            for (int d = 0; d < 128; ++d) {
                double wv = (double)W[(size_t)c * 128 + d];
                dot = fma((double)xrow[d], wv, dot);
                wsq = fma(wv, wv, wsq);
            }
            double dist = wsq - 2.0 * dot;
            if (dist < best || (dist == best && c < bi)) { best = dist; bi = c; }
        }
        for (int off = 1; off < 64; off <<= 1) {
            double ov = __shfl_xor(best, off, 64);
            int    oi = __shfl_xor(bi, off, 64);
            if (ov < best || (ov == best && oi < bi)) { best = ov; bi = oi; }
        }
        if ((tid & 63) == 0) { sv[tid >> 6] = best; si[tid >> 6] = bi; }
        __syncthreads();
        if (tid == 0) {
            for (int wv = 1; wv < 4; ++wv)
                if (sv[wv] < best || (sv[wv] == best && si[wv] < bi)) { best = sv[wv]; bi = si[wv]; }
            double x2 = 0.0;
            for (int d = 0; d < 128; ++d) { double xv = (double)xrow[d]; x2 = fma(xv, xv, x2); }
            cl_out[row] = (float)bi;
            atomicAdd(inertia_acc, x2 + best);
        }
        __syncthreads();
    }
}

__global__ void finalize_kernel(const float* __restrict__ W, const float* __restrict__ w2,
                                const double* __restrict__ inertia, float* __restrict__ out)
{
    __shared__ float sh1[128], sh2[128];
    int d = threadIdx.x;                       // 128 threads
    float s = 0.f;
    for (int k = 0; k < 1024; ++k) s += W[(size_t)k * 128 + d];
    float t = 0.f;
    for (int j = 0; j < 8; ++j) t += w2[d + 128 * j];
    sh1[d] = s * s;
    sh2[d] = t;
    __syncthreads();
    for (int off = 64; off > 0; off >>= 1) {
        if (d < off) { sh1[d] += sh1[d + off]; sh2[d] += sh2[d + off]; }
        __syncthreads();
    }
    if (d == 0) {
        float xe = 2.f * sh2[0] - sh1[0];
        out[1] = xe / 1024.f;
        out[0] = (float)(*inertia / 131072.0);
    }
}

extern "C" void kernel_launch(void* const* d_in, const int* in_sizes, int n_in,
                              void* d_out, int out_size, void* d_ws, size_t ws_size,
                              hipStream_t stream)
{
    const float* X = (const float*)d_in[0];          // [131072,128] f32
    const float* W = (const float*)d_in[1];          // [1024,128]   f32
    float* out = (float*)d_out;                       // [131074]     f32
    char* ws = (char*)d_ws;

    double* inertia  = (double*)ws;
    int*    flag_cnt = (int*)(ws + 8);
    float*  w2       = (float*)(ws + 16);
    short*  whl      = (short*)(ws + 8192);

    const size_t WHL_END = 8192 + 524288;            // 532480
    const bool precomp = ws_size >= WHL_END + 65536; // whl + headroom for flags

    int*   flag_rows;
    int    flag_cap;
    if (precomp) {
        flag_rows = (int*)(ws + WHL_END);
        long cap = ((long)ws_size - (long)WHL_END) / 4;
        flag_cap = cap > 131072 ? 131072 : (int)cap;
    } else {
        flag_rows = (int*)(ws + 8192);
        long cap = ((long)ws_size - 8192) / 4;
        flag_cap = cap < 0 ? 0 : (cap > 131072 ? 131072 : (int)cap);
    }

    hipMemsetAsync(ws, 0, 16, stream);               // inertia + flag_cnt

    wprep_kernel<<<1024, 128, 0, stream>>>(W, w2, whl, precomp ? 1 : 0);
    if (precomp) {
        dist_argmin_mfma<<<1024, 512, 0, stream>>>(X, whl, w2, out + 2, inertia,
                                                   flag_cnt, flag_rows, flag_cap);
    } else {
        dist_argmin_v2<<<1024, 512, 0, stream>>>(X, W, w2, out + 2, inertia,
                                                 flag_cnt, flag_rows, flag_cap);
    }
    refine_kernel<<<1024, 256, 0, stream>>>(X, W, flag_cnt, flag_rows, flag_cap,
                                            out + 2, inertia);
    finalize_kernel<<<1, 128, 0, stream>>>(W, w2, inertia, out);
}

// Round 4
// 170.992 us; speedup vs baseline: 3.6117x; 1.1831x over previous
//
#include <hip/hip_runtime.h>
#include <float.h>
#include <limits.h>
#include <math.h>

// ClusterLayer: B=131072 rows, K=1024 clusters, D=128.
// out (float32): [0] inertia/B, [1] xe/K, [2..2+B) cl as float.
//
// R4: 2 blocks/CU (72.3KB LDS), 64-col B tiles (16 iters), A fragments
// loaded global->registers directly, bf16 hi/lo 3-pass MFMA, counted-vmcnt
// double buffer, branch-free top-2 + f64 refine of near-ties.
//
// ws layout (bytes):
//   0      : double inertia_acc
//   8      : int    flag_cnt
//   16     : float  w2[1024]
//   8192   : short  whl[16 tiles][hi 8192 | lo 8192 shorts]   (524288 B)
//   532480 : int    flag_rows[...]

#define TAU 1e-3f

using bf16x8 = __attribute__((ext_vector_type(8))) short;
using f32x4  = __attribute__((ext_vector_type(4))) float;
using s16x4  = __attribute__((ext_vector_type(4))) short;

static __device__ __forceinline__ short f2bf_trunc(float f) {
    return (short)(__float_as_uint(f) >> 16);
}
static __device__ __forceinline__ float bf2f(short h) {
    return __uint_as_float(((unsigned int)(unsigned short)h) << 16);
}
static __device__ __forceinline__ bool lexlt(float v1, int i1, float v2, int i2) {
    return v1 < v2 || (v1 == v2 && i1 < i2);
}
static __device__ __forceinline__ void gload_lds16(const void* g, void* l) {
    __builtin_amdgcn_global_load_lds(
        (const __attribute__((address_space(1))) unsigned int*)g,
        (__attribute__((address_space(3))) unsigned int*)l, 16, 0, 0);
}
#define FENCE() do { asm volatile("" ::: "memory"); __builtin_amdgcn_sched_barrier(0); } while (0)

// W prep: w2 per cluster + bf16 hi/lo split in 64-col-tile fragment-image order.
// shorts: tile*16384 + plane*8192 + (c>>4)*2048 + (d>>5)*512 + ((d>>3)&3)*128 + (c&15)*8 + (d&7)
__global__ void wprep_kernel(const float* __restrict__ W, float* __restrict__ w2,
                             short* __restrict__ whl, int write_whl)
{
    const int k = blockIdx.x;      // cluster
    const int d = threadIdx.x;     // 0..127 dim
    float v = W[(size_t)k * 128 + d];
    float sq = v * v;
    for (int off = 1; off < 64; off <<= 1) sq += __shfl_xor(sq, off, 64);
    __shared__ float p[2];
    if ((d & 63) == 0) p[d >> 6] = sq;
    __syncthreads();
    if (d == 0) w2[k] = p[0] + p[1];
    if (write_whl) {
        short h = f2bf_trunc(v);
        short l = f2bf_trunc(v - bf2f(h));
        const int tile = k >> 6, c = k & 63;
        size_t base = (size_t)tile * 16384 + (size_t)(c >> 4) * 2048 + (size_t)(d >> 5) * 512
                    + (size_t)((d >> 3) & 3) * 128 + (size_t)(c & 15) * 8 + (size_t)(d & 7);
        whl[base]        = h;
        whl[base + 8192] = l;     // lo plane
    }
}

// LDS map (bytes): lB0 0..32768 | lB1 32768..65536 | lw2 65536(+4096) |
//                  lx2 69632(+512) | mscr 70144(+2048) | dred 72192(+128)
__global__ __launch_bounds__(512, 4)
void dist_argmin_mfma(const float* __restrict__ X, const short* __restrict__ whl,
                      const float* __restrict__ w2g, float* __restrict__ cl_out,
                      double* __restrict__ inertia_acc,
                      int* __restrict__ flag_cnt, int* __restrict__ flag_rows,
                      int flag_cap)
{
    __shared__ __align__(16) char smem[72320];
    char*   lB0  = smem;
    char*   lB1  = smem + 32768;
    float*  lw2  = (float*)(smem + 65536);
    float*  lx2  = (float*)(smem + 69632);
    int*    mscr = (int*)(smem + 70144);
    double* dred = (double*)(smem + 72192);

    const int tid    = threadIdx.x;
    const int lane   = tid & 63;
    const int laneLo = lane & 15;
    const int laneHi = lane >> 4;
    const int wid    = tid >> 6;
    const int rowg   = wid >> 1;
    const int colg   = wid & 1;
    const int rowbase = blockIdx.x * 128;

    // w2 -> LDS
    lw2[tid]       = w2g[tid];
    lw2[tid + 512] = w2g[tid + 512];

    // ---- A fragments straight from global into registers + per-row ||x||^2 ----
    // lane (laneLo,laneHi) holds A[row=rowg*32+m*16+laneLo][d=k0b*32+laneHi*8+j]
    bf16x8 ah[2][4], al[2][4];
    #pragma unroll
    for (int m = 0; m < 2; ++m) {
        const float* xp = X + (size_t)(rowbase + rowg * 32 + m * 16 + laneLo) * 128 + laneHi * 8;
        float s = 0.f;
        #pragma unroll
        for (int k0b = 0; k0b < 4; ++k0b) {
            float4 v0 = *reinterpret_cast<const float4*>(xp + k0b * 32);
            float4 v1 = *reinterpret_cast<const float4*>(xp + k0b * 32 + 4);
            float fv[8] = {v0.x, v0.y, v0.z, v0.w, v1.x, v1.y, v1.z, v1.w};
            bf16x8 hv, lv;
            #pragma unroll
            for (int u = 0; u < 8; ++u) {
                s = fmaf(fv[u], fv[u], s);
                short h = f2bf_trunc(fv[u]);
                short l = f2bf_trunc(fv[u] - bf2f(h));
                hv[u] = h; lv[u] = l;
            }
            ah[m][k0b] = hv; al[m][k0b] = lv;
        }
        s += __shfl_xor(s, 16, 64);     // combine the 4 laneHi slices
        s += __shfl_xor(s, 32, 64);
        if (colg == 0 && laneHi == 0) lx2[rowg * 32 + m * 16 + laneLo] = s;
    }
    asm volatile("s_waitcnt lgkmcnt(0)" ::: "memory");   // lw2/lx2 ds_writes drained
    __builtin_amdgcn_sched_barrier(0);

    // ---- issue B[0] -> lB0 (32 KB tile; wave wid copies its 4KB chunk) ----
    const char* wsrc = (const char*)whl;
    #pragma unroll
    for (int q = 0; q < 4; ++q)
        gload_lds16(wsrc + wid * 4096 + q * 1024 + lane * 16,
                    lB0 + wid * 4096 + q * 1024);
    wsrc += 32768;

    float t1v[2][4], t2v[2][4];
    int   t1i[2][4];
    #pragma unroll
    for (int m = 0; m < 2; ++m)
        #pragma unroll
        for (int r = 0; r < 4; ++r) {
            t1v[m][r] = FLT_MAX; t2v[m][r] = FLT_MAX; t1i[m][r] = INT_MAX;
        }

    const float* w2p = lw2 + colg * 32 + laneLo;
    int colbase = colg * 32 + laneLo;

    auto compute = [&](const char* pB) {
        const char* pBb = pB + colg * 8192 + lane * 16;
        __builtin_amdgcn_s_setprio(1);
        #pragma unroll
        for (int nt = 0; nt < 2; ++nt) {
            float w2v = w2p[nt * 16];
            f32x4 a0 = (f32x4){0.f, 0.f, 0.f, 0.f};
            f32x4 a1 = (f32x4){0.f, 0.f, 0.f, 0.f};
            #pragma unroll
            for (int k0b = 0; k0b < 4; ++k0b) {
                bf16x8 bh = *reinterpret_cast<const bf16x8*>(pBb + nt * 4096 + k0b * 1024);
                bf16x8 bl = *reinterpret_cast<const bf16x8*>(pBb + 16384 + nt * 4096 + k0b * 1024);
                a0 = __builtin_amdgcn_mfma_f32_16x16x32_bf16(ah[0][k0b], bh, a0, 0, 0, 0);
                a0 = __builtin_amdgcn_mfma_f32_16x16x32_bf16(ah[0][k0b], bl, a0, 0, 0, 0);
                a0 = __builtin_amdgcn_mfma_f32_16x16x32_bf16(al[0][k0b], bh, a0, 0, 0, 0);
                a1 = __builtin_amdgcn_mfma_f32_16x16x32_bf16(ah[1][k0b], bh, a1, 0, 0, 0);
                a1 = __builtin_amdgcn_mfma_f32_16x16x32_bf16(ah[1][k0b], bl, a1, 0, 0, 0);
                a1 = __builtin_amdgcn_mfma_f32_16x16x32_bf16(al[1][k0b], bh, a1, 0, 0, 0);
            }
            const int col = colbase + nt * 16;
            #pragma unroll
            for (int r = 0; r < 4; ++r) {
                float dv0 = fmaf(-2.f, a0[r], w2v);
                t2v[0][r] = fminf(t2v[0][r], fmaxf(t1v[0][r], dv0));
                t1i[0][r] = (dv0 < t1v[0][r]) ? col : t1i[0][r];
                t1v[0][r] = fminf(t1v[0][r], dv0);
                float dv1 = fmaf(-2.f, a1[r], w2v);
                t2v[1][r] = fminf(t2v[1][r], fmaxf(t1v[1][r], dv1));
                t1i[1][r] = (dv1 < t1v[1][r]) ? col : t1i[1][r];
                t1v[1][r] = fminf(t1v[1][r], dv1);
            }
        }
        __builtin_amdgcn_s_setprio(0);
    };

    const char* cur = lB0;
    char*       nxt = lB1;
    #pragma unroll 1
    for (int t = 0; t < 15; ++t) {
        // issue B[t+1] into the other buffer
        #pragma unroll
        for (int q = 0; q < 4; ++q)
            gload_lds16(wsrc + wid * 4096 + q * 1024 + lane * 16,
                        nxt + wid * 4096 + q * 1024);
        wsrc += 32768;
        asm volatile("s_waitcnt vmcnt(4)" ::: "memory");  // my B[t] landed; B[t+1] in flight
        __builtin_amdgcn_sched_barrier(0);
        __builtin_amdgcn_s_barrier();                     // everyone's B[t] landed
        FENCE();
        compute(cur);
        w2p += 64; colbase += 64;
        asm volatile("s_waitcnt lgkmcnt(0)" ::: "memory");
        __builtin_amdgcn_sched_barrier(0);
        __builtin_amdgcn_s_barrier();                     // all waves done reading cur
        FENCE();
        char* tmp = nxt; nxt = (char*)cur; cur = tmp;
    }
    asm volatile("s_waitcnt vmcnt(0)" ::: "memory");
    __builtin_amdgcn_sched_barrier(0);
    __builtin_amdgcn_s_barrier();
    FENCE();
    compute(cur);

    // ---- reduce top-2 across the 16 col-lanes (laneLo) of each row ----
    #pragma unroll
    for (int off = 1; off < 16; off <<= 1) {
        #pragma unroll
        for (int m = 0; m < 2; ++m)
            #pragma unroll
            for (int r = 0; r < 4; ++r) {
                float ov1 = __shfl_xor(t1v[m][r], off, 64);
                int   oi1 = __shfl_xor(t1i[m][r], off, 64);
                float ov2 = __shfl_xor(t2v[m][r], off, 64);
                float nt2 = fminf(fminf(t2v[m][r], ov2), fmaxf(t1v[m][r], ov1));
                if (lexlt(ov1, oi1, t1v[m][r], t1i[m][r])) { t1v[m][r] = ov1; t1i[m][r] = oi1; }
                t2v[m][r] = nt2;
            }
    }

    // ---- merge col-halves via LDS ----
    __syncthreads();
    if (colg == 1 && laneLo == 0) {
        #pragma unroll
        for (int m = 0; m < 2; ++m)
            #pragma unroll
            for (int r = 0; r < 4; ++r) {
                const int row = rowg * 32 + m * 16 + laneHi * 4 + r;
                mscr[row * 4 + 0] = __float_as_int(t1v[m][r]);
                mscr[row * 4 + 1] = t1i[m][r];
                mscr[row * 4 + 2] = __float_as_int(t2v[m][r]);
            }
    }
    __syncthreads();
    double local = 0.0;
    if (colg == 0 && laneLo == 0) {
        #pragma unroll
        for (int m = 0; m < 2; ++m)
            #pragma unroll
            for (int r = 0; r < 4; ++r) {
                const int row = rowg * 32 + m * 16 + laneHi * 4 + r;
                float ov1 = __int_as_float(mscr[row * 4 + 0]);
                int   oi1 = mscr[row * 4 + 1];
                float ov2 = __int_as_float(mscr[row * 4 + 2]);
                float b1v = t1v[m][r], b2v;
                int   b1i = t1i[m][r];
                b2v = fminf(fminf(t2v[m][r], ov2), fmaxf(b1v, ov1));
                if (lexlt(ov1, oi1, b1v, b1i)) { b1v = ov1; b1i = oi1; }
                const int grow = rowbase + row;
                const float gap = b2v - b1v;
                if (gap >= TAU) {
                    cl_out[grow] = (float)b1i;
                    local += (double)(b1v + lx2[row]);
                } else {
                    int slot = atomicAdd(flag_cnt, 1);
                    if (slot < flag_cap) {
                        flag_rows[slot] = grow;
                    } else {
                        cl_out[grow] = (float)b1i;
                        local += (double)(b1v + lx2[row]);
                    }
                }
            }
        dred[rowg * 4 + laneHi] = local;
    }
    __syncthreads();
    if (tid == 0) {
        double tt = 0.0;
        for (int i = 0; i < 16; ++i) tt += dred[i];
        atomicAdd(inertia_acc, tt);
    }
}

// ---------------- fallback (R2 kernel, used if ws too small) ----------------
__global__ __launch_bounds__(512, 1)
void dist_argmin_v2(const float* __restrict__ X, const float* __restrict__ W,
                    const float* __restrict__ w2g, float* __restrict__ cl_out,
                    double* __restrict__ inertia_acc,
                    int* __restrict__ flag_cnt, int* __restrict__ flag_rows,
                    int flag_cap)
{
    __shared__ __align__(16) char smem[133760];
    short*  Areg = (short*)smem;
    short*  Breg = (short*)(smem + 65536);
    int*    mscr = (int*)(smem + 131072);
    float*  lx2  = (float*)(smem + 131072 + 2048);
    double* dred = (double*)(smem + 131072 + 2048 + 512);

    const int tid    = threadIdx.x;
    const int lane   = tid & 63;
    const int laneLo = lane & 15;
    const int laneHi = lane >> 4;
    const int wid    = tid >> 6;
    const int rowg   = wid >> 1;
    const int colg   = wid & 1;
    const int rowbase = blockIdx.x * 128;

    {
        const int r = tid >> 2, q = tid & 3;
        float s = 0.f;
        #pragma unroll
        for (int j = 0; j < 8; ++j) {
            const int d0 = q * 4 + j * 16;
            float4 v = *reinterpret_cast<const float4*>(X + (size_t)(rowbase + r) * 128 + d0);
            float fv[4] = {v.x, v.y, v.z, v.w};
            s16x4 hv, lv;
            #pragma unroll
            for (int u = 0; u < 4; ++u) {
                s = fmaf(fv[u], fv[u], s);
                short h = f2bf_trunc(fv[u]);
                short l = f2bf_trunc(fv[u] - bf2f(h));
                hv[u] = h; lv[u] = l;
            }
            const int kb = d0 >> 3, off = d0 & 7;
            short* pa = Areg + (kb * 128 + r) * 8 + off;
            *reinterpret_cast<s16x4*>(pa)         = hv;
            *reinterpret_cast<s16x4*>(pa + 16384) = lv;
        }
        s += __shfl_xor(s, 1, 64);
        s += __shfl_xor(s, 2, 64);
        if (q == 0) lx2[r] = s;
    }

    float t1v[2][4], t2v[2][4];
    int   t1i[2][4];
    #pragma unroll
    for (int m = 0; m < 2; ++m)
        #pragma unroll
        for (int r = 0; r < 4; ++r) {
            t1v[m][r] = FLT_MAX; t2v[m][r] = FLT_MAX; t1i[m][r] = INT_MAX;
        }

    const char* pAbase = smem + laneHi * 2048 + (rowg * 32 + laneLo) * 16;
    const char* pBbase = smem + 65536 + colg * 16384 + lane * 16;

    for (int iter = 0; iter < 8; ++iter) {
        __syncthreads();
        {
            const int c = tid >> 2, q = tid & 3;
            const int nt = c >> 4, c15 = c & 15;
            #pragma unroll
            for (int j = 0; j < 8; ++j) {
                const int d0 = q * 4 + j * 16;
                float4 v = *reinterpret_cast<const float4*>(W + (size_t)(iter * 128 + c) * 128 + d0);
                float fv[4] = {v.x, v.y, v.z, v.w};
                s16x4 hv, lv;
                #pragma unroll
                for (int u = 0; u < 4; ++u) {
                    short h = f2bf_trunc(fv[u]);
                    short l = f2bf_trunc(fv[u] - bf2f(h));
                    hv[u] = h; lv[u] = l;
                }
                const int k0b = d0 >> 5, sub = (d0 >> 3) & 3, jj = d0 & 7;
                short* pb = Breg + ((nt * 4 + k0b) * 64 + sub * 16 + c15) * 8 + jj;
                *reinterpret_cast<s16x4*>(pb)         = hv;
                *reinterpret_cast<s16x4*>(pb + 16384) = lv;
            }
        }
        float w2v[4];
        #pragma unroll
        for (int nt = 0; nt < 4; ++nt)
            w2v[nt] = w2g[iter * 128 + colg * 64 + nt * 16 + laneLo];
        __syncthreads();

        f32x4 acc[2][4];
        #pragma unroll
        for (int m = 0; m < 2; ++m)
            #pragma unroll
            for (int nt = 0; nt < 4; ++nt)
                acc[m][nt] = (f32x4){0.f, 0.f, 0.f, 0.f};

        #pragma unroll
        for (int k0b = 0; k0b < 4; ++k0b) {
            bf16x8 ah[2], al[2];
            #pragma unroll
            for (int m = 0; m < 2; ++m) {
                ah[m] = *reinterpret_cast<const bf16x8*>(pAbase + k0b * 8192 + m * 256);
                al[m] = *reinterpret_cast<const bf16x8*>(pAbase + 32768 + k0b * 8192 + m * 256);
            }
            #pragma unroll
            for (int nt = 0; nt < 4; ++nt) {
                bf16x8 bh = *reinterpret_cast<const bf16x8*>(pBbase + nt * 4096 + k0b * 1024);
                bf16x8 bl = *reinterpret_cast<const bf16x8*>(pBbase + 32768 + nt * 4096 + k0b * 1024);
                #pragma unroll
                for (int m = 0; m < 2; ++m) {
                    acc[m][nt] = __builtin_amdgcn_mfma_f32_16x16x32_bf16(ah[m], bh, acc[m][nt], 0, 0, 0);
                    acc[m][nt] = __builtin_amdgcn_mfma_f32_16x16x32_bf16(ah[m], bl, acc[m][nt], 0, 0, 0);
                    acc[m][nt] = __builtin_amdgcn_mfma_f32_16x16x32_bf16(al[m], bh, acc[m][nt], 0, 0, 0);
                }
            }
        }

        #pragma unroll
        for (int nt = 0; nt < 4; ++nt) {
            const int col = iter * 128 + colg * 64 + nt * 16 + laneLo;
            #pragma unroll
            for (int m = 0; m < 2; ++m)
                #pragma unroll
                for (int r = 0; r < 4; ++r) {
                    float dv = fmaf(-2.f, acc[m][nt][r], w2v[nt]);
                    float hi = fmaxf(t1v[m][r], dv);
                    t2v[m][r] = fminf(t2v[m][r], hi);
                    bool cnd = dv < t1v[m][r];
                    t1i[m][r] = cnd ? col : t1i[m][r];
                    t1v[m][r] = fminf(t1v[m][r], dv);
                }
        }
    }

    #pragma unroll
    for (int off = 1; off < 16; off <<= 1) {
        #pragma unroll
        for (int m = 0; m < 2; ++m)
            #pragma unroll
            for (int r = 0; r < 4; ++r) {
                float ov1 = __shfl_xor(t1v[m][r], off, 64);
                int   oi1 = __shfl_xor(t1i[m][r], off, 64);
                float ov2 = __shfl_xor(t2v[m][r], off, 64);
                float nt2 = fminf(fminf(t2v[m][r], ov2), fmaxf(t1v[m][r], ov1));
                if (lexlt(ov1, oi1, t1v[m][r], t1i[m][r])) { t1v[m][r] = ov1; t1i[m][r] = oi1; }
                t2v[m][r] = nt2;
            }
    }

    __syncthreads();
    if (colg == 1 && laneLo == 0) {
        #pragma unroll
        for (int m = 0; m < 2; ++m)
            #pragma unroll
            for (int r = 0; r < 4; ++r) {
                const int row = rowg * 32 + m * 16 + laneHi * 4 + r;
                mscr[row * 4 + 0] = __float_as_int(t1v[m][r]);
                mscr[row * 4 + 1] = t1i[m][r];
                mscr[row * 4 + 2] = __float_as_int(t2v[m][r]);
            }
    }
    __syncthreads();
    double local = 0.0;
    if (colg == 0 && laneLo == 0) {
        #pragma unroll
        for (int m = 0; m < 2; ++m)
            #pragma unroll
            for (int r = 0; r < 4; ++r) {
                const int row = rowg * 32 + m * 16 + laneHi * 4 + r;
                float ov1 = __int_as_float(mscr[row * 4 + 0]);
                int   oi1 = mscr[row * 4 + 1];
                float ov2 = __int_as_float(mscr[row * 4 + 2]);
                float b1v = t1v[m][r], b2v;
                int   b1i = t1i[m][r];
                b2v = fminf(fminf(t2v[m][r], ov2), fmaxf(b1v, ov1));
                if (lexlt(ov1, oi1, b1v, b1i)) { b1v = ov1; b1i = oi1; }
                const int grow = rowbase + row;
                const float gap = b2v - b1v;
                if (gap >= TAU) {
                    cl_out[grow] = (float)b1i;
                    local += (double)(b1v + lx2[row]);
                } else {
                    int slot = atomicAdd(flag_cnt, 1);
                    if (slot < flag_cap) flag_rows[slot] = grow;
                    else { cl_out[grow] = (float)b1i; local += (double)(b1v + lx2[row]); }
                }
            }
        dred[rowg * 4 + laneHi] = local;
    }
    __syncthreads();
    if (tid == 0) {
        double t = 0.0;
        for (int i = 0; i < 16; ++i) t += dred[i];
        atomicAdd(inertia_acc, t);
    }
}

// exact f64 argmin over all 1024 clusters for flagged (near-tie) rows
__global__ void refine_kernel(const float* __restrict__ X, const float* __restrict__ W,
                              const int* __restrict__ flag_cnt, const int* __restrict__ flag_rows,
                              int flag_cap, float* __restrict__ cl_out,
                              double* __restrict__ inertia_acc)
{
    __shared__ double sv[4];
    __shared__ int    si[4];
    __shared__ float  xrow[128];
    int n = *flag_cnt;
    if (n > flag_cap) n = flag_cap;
    const int tid = threadIdx.x;

    for (int f = blockIdx.x; f < n; f += gridDim.x) {
        int row = flag_rows[f];
        if (tid < 128) xrow[tid] = X[(size_t)row * 128 + tid];
        __syncthreads();

        double best = DBL_MAX; int bi = INT_MAX;
        for (int cc = 0; cc < 4; ++cc) {
            int c = tid + 256 * cc;
            double dot = 0.0, wsq = 0.0;
            for (int d = 0; d < 128; ++d) {
                double wv = (double)W[(size_t)c * 128 + d];
                dot = fma((double)xrow[d], wv, dot);
                wsq = fma(wv, wv, wsq);
            }
            double dist = wsq - 2.0 * dot;
            if (dist < best || (dist == best && c < bi)) { best = dist; bi = c; }
        }
        for (int off = 1; off < 64; off <<= 1) {
            double ov = __shfl_xor(best, off, 64);
            int    oi = __shfl_xor(bi, off, 64);
            if (ov < best || (ov == best && oi < bi)) { best = ov; bi = oi; }
        }
        if ((tid & 63) == 0) { sv[tid >> 6] = best; si[tid >> 6] = bi; }
        __syncthreads();
        if (tid == 0) {
            for (int wv = 1; wv < 4; ++wv)
                if (sv[wv] < best || (sv[wv] == best && si[wv] < bi)) { best = sv[wv]; bi = si[wv]; }
            double x2 = 0.0;
            for (int d = 0; d < 128; ++d) { double xv = (double)xrow[d]; x2 = fma(xv, xv, x2); }
            cl_out[row] = (float)bi;
            atomicAdd(inertia_acc, x2 + best);
        }
        __syncthreads();
    }
}

__global__ void finalize_kernel(const float* __restrict__ W, const float* __restrict__ w2,
                                const double* __restrict__ inertia, float* __restrict__ out)
{
    __shared__ float sh1[128], sh2[128];
    int d = threadIdx.x;                       // 128 threads
    float s = 0.f;
    for (int k = 0; k < 1024; ++k) s += W[(size_t)k * 128 + d];
    float t = 0.f;
    for (int j = 0; j < 8; ++j) t += w2[d + 128 * j];
    sh1[d] = s * s;
    sh2[d] = t;
    __syncthreads();
    for (int off = 64; off > 0; off >>= 1) {
        if (d < off) { sh1[d] += sh1[d + off]; sh2[d] += sh2[d + off]; }
        __syncthreads();
    }
    if (d == 0) {
        float xe = 2.f * sh2[0] - sh1[0];
        out[1] = xe / 1024.f;
        out[0] = (float)(*inertia / 131072.0);
    }
}

extern "C" void kernel_launch(void* const* d_in, const int* in_sizes, int n_in,
                              void* d_out, int out_size, void* d_ws, size_t ws_size,
                              hipStream_t stream)
{
    const float* X = (const float*)d_in[0];          // [131072,128] f32
    const float* W = (const float*)d_in[1];          // [1024,128]   f32
    float* out = (float*)d_out;                       // [131074]     f32
    char* ws = (char*)d_ws;

    double* inertia  = (double*)ws;
    int*    flag_cnt = (int*)(ws + 8);
    float*  w2       = (float*)(ws + 16);
    short*  whl      = (short*)(ws + 8192);

    const size_t WHL_END = 8192 + 524288;            // 532480
    const bool precomp = ws_size >= WHL_END + 65536; // whl + headroom for flags

    int*   flag_rows;
    int    flag_cap;
    if (precomp) {
        flag_rows = (int*)(ws + WHL_END);
        long cap = ((long)ws_size - (long)WHL_END) / 4;
        flag_cap = cap > 131072 ? 131072 : (int)cap;
    } else {
        flag_rows = (int*)(ws + 8192);
        long cap = ((long)ws_size - 8192) / 4;
        flag_cap = cap < 0 ? 0 : (cap > 131072 ? 131072 : (int)cap);
    }

    hipMemsetAsync(ws, 0, 16, stream);               // inertia + flag_cnt

    wprep_kernel<<<1024, 128, 0, stream>>>(W, w2, whl, precomp ? 1 : 0);
    if (precomp) {
        dist_argmin_mfma<<<1024, 512, 0, stream>>>(X, whl, w2, out + 2, inertia,
                                                   flag_cnt, flag_rows, flag_cap);
    } else {
        dist_argmin_v2<<<1024, 512, 0, stream>>>(X, W, w2, out + 2, inertia,
                                                 flag_cnt, flag_rows, flag_cap);
    }
    refine_kernel<<<1024, 256, 0, stream>>>(X, W, flag_cnt, flag_rows, flag_cap,
                                            out + 2, inertia);
    finalize_kernel<<<1, 128, 0, stream>>>(W, w2, inertia, out);
}